// Round 11
// baseline (380.155 us; speedup 1.0000x reference)
//
#include <hip/hip_runtime.h>
#include <hip/hip_bf16.h>

// GCN_27676769256197 round 11: decouple degF from GEMM; fuse pass2 + gemm1.
//   - deg_o scaling moved into the gathers (per-edge broadcast degF[src] load,
//     fused multiply into the row sum) -> gemm1 depends only on prep1
//   - mid dispatch = pass2 dst-place + pass2b src-count + ALL layer-1 GEMMs:
//     pass2's latency-bound blocks co-schedule with MFMA waves (m114 overlap)
//   - pipeline: memset -> prep1 -> mid -> gather0 -> gemm2 -> gather1 (6)
//   - bucket-sort CSR build, fixed-capacity uint16 rows, gather cores with
//     4-edge unroll (8 loads in flight incl. degF) unchanged otherwise

#define N_W 50000
#define N_D 20000
#define E_WW 500000
#define E_WD 300000
#define NTOT 170000

#define C_WW 40
#define C_WD 48
#define C_DWR 32

#define NB_WW 196    // dst buckets (padded rows/256)
#define NB_WD 79
#define NB_DWR 196
#define CAPB_WW 2816
#define CAPB_WD 4096
#define CAPB_DWR 1792

#define NBS_W 196    // src buckets, word-space relations (ww/wwr/wd)
#define NBS_D 79     // src buckets, doc-space (dwr)
#define CAPS_WW 2816
#define CAPS_WD 1792
#define CAPS_DWR 4352

typedef __attribute__((ext_vector_type(8))) short short8;
typedef __attribute__((ext_vector_type(4))) float f32x4;

static __device__ __forceinline__ unsigned f2bf_u(float x) {
  unsigned u = __float_as_uint(x);
  return (u + 0x7fff + ((u >> 16) & 1)) >> 16;  // RNE
}
static __device__ __forceinline__ unsigned short f2bf(float x) {
  return (unsigned short)f2bf_u(x);
}
static __device__ __forceinline__ float bf2f(unsigned short b) {
  return __uint_as_float((unsigned)b << 16);
}
static __device__ __forceinline__ void gld16(const void* g, void* l) {
  __builtin_amdgcn_global_load_lds(
      (const __attribute__((address_space(1))) void*)g,
      (__attribute__((address_space(3))) void*)l, 16, 0, 0);
}

struct Args {
  const float *x_word, *x_doc;
  const int *src_ww, *dst_ww, *src_wd, *dst_wd, *src_wwr, *dst_wwr, *src_dwr, *dst_dwr;
  const float *W1_ww, *W1_wd, *W1_wwr, *W1_dwr;
  const float *W2_ww, *W2_wd, *W2_wwr, *W2_dwr;
  const float *b1_ww, *b1_wd, *b1_wwr, *b1_dwr;
  const float *b2_ww, *b2_wd, *b2_wwr, *b2_dwr;
  const float *lin_w, *lin_b;
  float *out;
  int *cnt256d;  // [4][256] dst bucket cursors (zeroed)
  int *cnt256s;  // [4][256] src bucket cursors (zeroed)
  int *cur;      // [NTOT] dst in-degrees
  float *degF;   // [NTOT] rsqrt(out-degree): ww@0 wwr@50k wd@100k dwr@150k
  unsigned short *csr_ww, *csr_wwr, *csr_wd, *csr_dwr;
  unsigned int *stg_ww, *stg_wwr, *stg_wd, *stg_dwr;       // dst staging
  unsigned char *sst_ww, *sst_wwr, *sst_wd, *sst_dwr;      // src staging (bytes)
  unsigned short *xw_bf, *xd_bf, *h_w3, *h_d, *Bt1w, *Bt1d, *Bt2w, *Bt2d;
  unsigned short *accW1, *accD1;
};

#define BS_WW 123
#define BS_WD 74
#define BV_W 12500
#define BV_D 5000
#define BP1W 384
#define BP1D 128
#define BP2W 192
#define BP2D 64
#define BG_W 391
#define BG_D 157
#define BGR_W 6250
#define BGR_D 2500

// --------------------------------------------------------------- pass 1 -----
static __device__ __forceinline__ void lds_scan256(int* cnt, int* bas, int* scn) {
  const int t = threadIdx.x;
  scn[t] = cnt[t];
  __syncthreads();
#pragma unroll
  for (int off = 1; off < 256; off <<= 1) {
    int v = (t >= off) ? scn[t - off] : 0;
    __syncthreads();
    scn[t] += v;
    __syncthreads();
  }
  bas[t] = scn[t] - cnt[t];
  scn[t] = bas[t];
  __syncthreads();
}

static __device__ void dev_pass1(
    const int* __restrict__ src, const int* __restrict__ dst, int E,
    unsigned int* __restrict__ stageD, int CAPBD, int* __restrict__ cntD,
    unsigned char* __restrict__ stageS, int CAPBS, int* __restrict__ cntS,
    int lb, int* cnt, int* bas, int* scn, unsigned int* lstage) {
  const int t = threadIdx.x;
  const int eb = lb * 4096;
  unsigned int w[16];
  cnt[t] = 0;
  __syncthreads();
#pragma unroll
  for (int u = 0; u < 16; u++) {
    int e = eb + u * 256 + t;
    if (e < E) {
      int s = src[e], d = dst[e];
      w[u] = ((unsigned)s << 16) | (unsigned)d;
      atomicAdd(&cnt[d >> 8], 1);
    } else {
      w[u] = 0xFFFFFFFFu;
    }
  }
  __syncthreads();
  lds_scan256(cnt, bas, scn);
#pragma unroll
  for (int u = 0; u < 16; u++) {
    if (w[u] != 0xFFFFFFFFu) {
      int bk = (w[u] & 0xFFFFu) >> 8;
      int p = atomicAdd(&scn[bk], 1);
      lstage[p] = w[u];
    }
  }
  __syncthreads();
  {
    int n = cnt[t];
    if (n > 0) {
      int g = atomicAdd(&cntD[t], n);
      unsigned int* dp = stageD + (size_t)t * CAPBD + g;
      int lb2 = bas[t];
      for (int k = 0; k < n; k++)
        if (g + k < CAPBD) dp[k] = lstage[lb2 + k];
    }
  }
  __syncthreads();
  // ---- round 2: src binning, 1-byte payload ----
  cnt[t] = 0;
  __syncthreads();
#pragma unroll
  for (int u = 0; u < 16; u++)
    if (w[u] != 0xFFFFFFFFu) atomicAdd(&cnt[w[u] >> 24], 1);
  __syncthreads();
  lds_scan256(cnt, bas, scn);
  unsigned char* lbytes = (unsigned char*)lstage;
#pragma unroll
  for (int u = 0; u < 16; u++) {
    if (w[u] != 0xFFFFFFFFu) {
      int bk = w[u] >> 24;
      int p = atomicAdd(&scn[bk], 1);
      lbytes[p] = (unsigned char)((w[u] >> 16) & 0xFF);
    }
  }
  __syncthreads();
  {
    int n = cnt[t];
    if (n > 0) {
      int g = atomicAdd(&cntS[t], n);
      unsigned char* dp = stageS + (size_t)t * CAPBS + g;
      int lb2 = bas[t];
      for (int k = 0; k < n; k++)
        if (g + k < CAPBS) dp[k] = lbytes[lb2 + k];
    }
  }
}

static __device__ __forceinline__ void dev_cvt(
    const float* __restrict__ x, unsigned short* __restrict__ y, int i, int n4) {
  if (i < n4) {
    float4 v = ((const float4*)x)[i];
    ushort4 u;
    u.x = f2bf(v.x); u.y = f2bf(v.y); u.z = f2bf(v.z); u.w = f2bf(v.w);
    ((ushort4*)y)[i] = u;
  }
}
static __device__ __forceinline__ void dev_packB(
    const float* __restrict__ W0, const float* __restrict__ W1,
    const float* __restrict__ W2, int kshift, int total, int i,
    unsigned short* __restrict__ out) {
  if (i >= total) return;
  int n = i >> kshift, k = i & ((1 << kshift) - 1);
  const float* W = (n < 128) ? W0 : ((n < 256) ? W1 : W2);
  out[i] = f2bf(W[(size_t)k * 128 + (n & 127)]);
}

__global__ __launch_bounds__(256) void prep1_kernel(Args a) {
  __shared__ int cnt[256], bas[256], scn[256];
  __shared__ unsigned int lstage[4096];
  int b = blockIdx.x;
  const int t = threadIdx.x;
  if (b < BS_WW) { dev_pass1(a.src_ww, a.dst_ww, E_WW, a.stg_ww, CAPB_WW, a.cnt256d, a.sst_ww, CAPS_WW, a.cnt256s, b, cnt, bas, scn, lstage); return; }
  b -= BS_WW;
  if (b < BS_WW) { dev_pass1(a.src_wwr, a.dst_wwr, E_WW, a.stg_wwr, CAPB_WW, a.cnt256d + 256, a.sst_wwr, CAPS_WW, a.cnt256s + 256, b, cnt, bas, scn, lstage); return; }
  b -= BS_WW;
  if (b < BS_WD) { dev_pass1(a.src_wd, a.dst_wd, E_WD, a.stg_wd, CAPB_WD, a.cnt256d + 512, a.sst_wd, CAPS_WD, a.cnt256s + 512, b, cnt, bas, scn, lstage); return; }
  b -= BS_WD;
  if (b < BS_WD) { dev_pass1(a.src_dwr, a.dst_dwr, E_WD, a.stg_dwr, CAPB_DWR, a.cnt256d + 768, a.sst_dwr, CAPS_DWR, a.cnt256s + 768, b, cnt, bas, scn, lstage); return; }
  b -= BS_WD;
  if (b < BV_W) { dev_cvt(a.x_word, a.xw_bf, b * 256 + t, N_W * 64); return; }
  b -= BV_W;
  if (b < BV_D) { dev_cvt(a.x_doc, a.xd_bf, b * 256 + t, N_D * 64); return; }
  b -= BV_D;
  if (b < BP1W) { dev_packB(a.W1_ww, a.W1_wwr, a.W1_wd, 8, 384 * 256, b * 256 + t, a.Bt1w); return; }
  b -= BP1W;
  if (b < BP1D) { dev_packB(a.W1_dwr, a.W1_dwr, a.W1_dwr, 8, 128 * 256, b * 256 + t, a.Bt1d); return; }
  b -= BP1D;
  if (b < BP2W) { dev_packB(a.W2_ww, a.W2_wwr, a.W2_wd, 7, 384 * 128, b * 256 + t, a.Bt2w); return; }
  b -= BP2W;
  dev_packB(a.W2_dwr, a.W2_dwr, a.W2_dwr, 7, 128 * 128, b * 256 + t, a.Bt2d);
}

// -------------------------------------------------- pass 2 device pieces ----
static __device__ void dev_pass2(
    const unsigned int* __restrict__ stage, int CAPB, int C, int Nrel,
    const int* __restrict__ cntD, int* __restrict__ curRel,
    unsigned short* __restrict__ csr, int b,
    int* cnt2, unsigned short* slice) {
  const int t = threadIdx.x;
  cnt2[t] = 0;
  __syncthreads();
  int n = cntD[b];
  if (n > CAPB) n = CAPB;
  const unsigned int* sp = stage + (size_t)b * CAPB;
  for (int e = t; e < n; e += 256) {
    unsigned int w = sp[e];
    int dl = w & 0xFF;
    int s = w >> 16;
    int p = atomicAdd(&cnt2[dl], 1);
    if (p < C) slice[dl * C + p] = (unsigned short)s;
  }
  __syncthreads();
  const int words = 256 * C / 2;
  unsigned int* g32 = (unsigned int*)csr + (size_t)b * (128 * C);
  const unsigned int* s32 = (const unsigned int*)slice;
  for (int i = t; i < words; i += 256) g32[i] = s32[i];
  int node = b * 256 + t;
  if (node < Nrel) curRel[node] = cnt2[t];
}

static __device__ void dev_pass2b(
    const unsigned char* __restrict__ stage, int CAPB, int Nrel,
    const int* __restrict__ cntS, float* __restrict__ degFRel, int b,
    int* cnt2) {
  const int t = threadIdx.x;
  cnt2[t] = 0;
  __syncthreads();
  int n = cntS[b];
  if (n > CAPB) n = CAPB;
  const unsigned char* sp = stage + (size_t)b * CAPB;
  for (int e = t; e < n; e += 256) atomicAdd(&cnt2[sp[e]], 1);
  __syncthreads();
  int node = b * 256 + t;
  if (node < Nrel) degFRel[node] = rsqrtf(fmaxf((float)cnt2[t], 1.0f));
}

// -------------------------------------------------------------- GEMM core ---
// (no deg scale — raw bf16(acc); degF applied in the gathers)
template <int K>
static __device__ void dev_gemm(
    const unsigned short* __restrict__ A, int M,
    const unsigned short* __restrict__ BtSub,
    unsigned short* __restrict__ C, int cstride, int coloff,
    int bx, unsigned char* smem) {
  const int row0 = bx * 128;
  const int tid = threadIdx.x;
  const int lane = tid & 63;
  const int wave = tid >> 6;
  const int wr = wave >> 1;
  const int wc = wave & 1;
  const int lc = lane & 15;
  const int quad = lane >> 4;

  unsigned char* sA = smem;
  unsigned char* sB = smem + 16384;
  const int mn = tid & 127;
  const int kc0 = tid >> 7;
  const unsigned short* arow = A + (size_t)(row0 + mn) * K;
  const unsigned short* brow = BtSub + (size_t)mn * K;
  unsigned char* ldsA = sA + wave * 1024;
  unsigned char* ldsB = sB + wave * 1024;

  f32x4 acc[4][4];
#pragma unroll
  for (int p = 0; p < 4; p++)
#pragma unroll
    for (int q = 0; q < 4; q++) acc[p][q] = {0.f, 0.f, 0.f, 0.f};

  for (int k0 = 0; k0 < K; k0 += 64) {
#pragma unroll
    for (int i = 0; i < 4; i++) {
      int kk = k0 + (i * 2 + kc0) * 8;
      gld16(arow + kk, ldsA + i * 4096);
      gld16(brow + kk, ldsB + i * 4096);
    }
    __syncthreads();
#pragma unroll
    for (int s = 0; s < 2; s++) {
      const int ko = (s * 4 + quad) * 2048 + lc * 16;
      short8 av[4], bv[4];
#pragma unroll
      for (int p = 0; p < 4; p++)
        av[p] = *(const short8*)(sA + ko + (wr * 64 + p * 16) * 16);
#pragma unroll
      for (int q = 0; q < 4; q++)
        bv[q] = *(const short8*)(sB + ko + (wc * 64 + q * 16) * 16);
#pragma unroll
      for (int p = 0; p < 4; p++)
#pragma unroll
        for (int q = 0; q < 4; q++)
          acc[p][q] = __builtin_amdgcn_mfma_f32_16x16x32_bf16(
              av[p], bv[q], acc[p][q], 0, 0, 0);
    }
    __syncthreads();
  }

  const int colb = coloff + wc * 64;
#pragma unroll
  for (int p = 0; p < 4; p++) {
#pragma unroll
    for (int i = 0; i < 4; i++) {
      int r = row0 + wr * 64 + p * 16 + quad * 4 + i;
      if (r >= M) continue;
      unsigned short* cp = C + (size_t)r * cstride + colb + lc;
#pragma unroll
      for (int q = 0; q < 4; q++) cp[q * 16] = f2bf(acc[p][q][i]);
    }
  }
}

// -------------------------------- mid: pass2 (all) + layer-1 GEMMs (fused) --
__global__ __launch_bounds__(256) void mid_kernel(Args a) {
  __shared__ __align__(16) unsigned char smem[32768];
  __shared__ int cnt2[256];
  int b = blockIdx.x;
  if (b < NB_WW) { dev_pass2(a.stg_ww, CAPB_WW, C_WW, N_W, a.cnt256d, a.cur, a.csr_ww, b, cnt2, (unsigned short*)smem); return; }
  b -= NB_WW;
  if (b < NB_WW) { dev_pass2(a.stg_wwr, CAPB_WW, C_WW, N_W, a.cnt256d + 256, a.cur + 50000, a.csr_wwr, b, cnt2, (unsigned short*)smem); return; }
  b -= NB_WW;
  if (b < NB_WD) { dev_pass2(a.stg_wd, CAPB_WD, C_WD, N_D, a.cnt256d + 512, a.cur + 100000, a.csr_wd, b, cnt2, (unsigned short*)smem); return; }
  b -= NB_WD;
  if (b < NB_DWR) { dev_pass2(a.stg_dwr, CAPB_DWR, C_DWR, N_W, a.cnt256d + 768, a.cur + 120000, a.csr_dwr, b, cnt2, (unsigned short*)smem); return; }
  b -= NB_DWR;
  if (b < NBS_W) { dev_pass2b(a.sst_ww, CAPS_WW, N_W, a.cnt256s, a.degF, b, cnt2); return; }
  b -= NBS_W;
  if (b < NBS_W) { dev_pass2b(a.sst_wwr, CAPS_WW, N_W, a.cnt256s + 256, a.degF + 50000, b, cnt2); return; }
  b -= NBS_W;
  if (b < NBS_W) { dev_pass2b(a.sst_wd, CAPS_WD, N_W, a.cnt256s + 512, a.degF + 100000, b, cnt2); return; }
  b -= NBS_W;
  if (b < NBS_D) { dev_pass2b(a.sst_dwr, CAPS_DWR, N_D, a.cnt256s + 768, a.degF + 150000, b, cnt2); return; }
  b -= NBS_D;
  if (b < BG_W) { dev_gemm<256>(a.xw_bf, N_W, a.Bt1w,                     a.h_w3, 384, 0,   b, smem); return; }
  b -= BG_W;
  if (b < BG_W) { dev_gemm<256>(a.xw_bf, N_W, a.Bt1w + (size_t)128 * 256, a.h_w3, 384, 128, b, smem); return; }
  b -= BG_W;
  if (b < BG_W) { dev_gemm<256>(a.xw_bf, N_W, a.Bt1w + (size_t)256 * 256, a.h_w3, 384, 256, b, smem); return; }
  b -= BG_W;
  dev_gemm<256>(a.xd_bf, N_D, a.Bt1d, a.h_d, 128, 0, b, smem);
}

// ----------------------------------------------------------- layer-2 GEMM ---
__global__ __launch_bounds__(256) void gemm2_kernel(Args a) {
  __shared__ __align__(16) unsigned char smem[32768];
  int b = blockIdx.x;
  if (b < BG_W) { dev_gemm<128>(a.accW1, N_W, a.Bt2w,                     a.h_w3, 384, 0,   b, smem); return; }
  b -= BG_W;
  if (b < BG_W) { dev_gemm<128>(a.accW1, N_W, a.Bt2w + (size_t)128 * 128, a.h_w3, 384, 128, b, smem); return; }
  b -= BG_W;
  if (b < BG_W) { dev_gemm<128>(a.accW1, N_W, a.Bt2w + (size_t)256 * 128, a.h_w3, 384, 256, b, smem); return; }
  b -= BG_W;
  dev_gemm<128>(a.accD1, N_D, a.Bt2d, a.h_d, 128, 0, b, smem);
}

// ---------------------------------------------------------------- gathers ---
// per-edge: row * degF[src] (broadcast load, issued with the row load)
static __device__ __forceinline__ float4 edge_sum32(
    const unsigned short* __restrict__ base, int stride,
    const unsigned short* __restrict__ csr, const float* __restrict__ degF,
    int st, int en, int lane32) {
  float4 s0 = make_float4(0.f, 0.f, 0.f, 0.f);
  float4 s1 = make_float4(0.f, 0.f, 0.f, 0.f);
  float4 s2 = make_float4(0.f, 0.f, 0.f, 0.f);
  float4 s3 = make_float4(0.f, 0.f, 0.f, 0.f);
  for (int b = st; b < en; b += 32) {
    int n = en - b; if (n > 32) n = 32;
    int t = b + lane32;
    int idx = csr[t < en ? t : en - 1];
    int j = 0;
    for (; j + 3 < n; j += 4) {
      int e0 = __shfl(idx, j, 32), e1 = __shfl(idx, j + 1, 32);
      int e2 = __shfl(idx, j + 2, 32), e3 = __shfl(idx, j + 3, 32);
      float f0 = degF[e0], f1 = degF[e1], f2 = degF[e2], f3 = degF[e3];
      ushort4 u0 = *(const ushort4*)(base + (size_t)e0 * stride);
      ushort4 u1 = *(const ushort4*)(base + (size_t)e1 * stride);
      ushort4 u2 = *(const ushort4*)(base + (size_t)e2 * stride);
      ushort4 u3 = *(const ushort4*)(base + (size_t)e3 * stride);
      s0.x += bf2f(u0.x) * f0; s0.y += bf2f(u0.y) * f0; s0.z += bf2f(u0.z) * f0; s0.w += bf2f(u0.w) * f0;
      s1.x += bf2f(u1.x) * f1; s1.y += bf2f(u1.y) * f1; s1.z += bf2f(u1.z) * f1; s1.w += bf2f(u1.w) * f1;
      s2.x += bf2f(u2.x) * f2; s2.y += bf2f(u2.y) * f2; s2.z += bf2f(u2.z) * f2; s2.w += bf2f(u2.w) * f2;
      s3.x += bf2f(u3.x) * f3; s3.y += bf2f(u3.y) * f3; s3.z += bf2f(u3.z) * f3; s3.w += bf2f(u3.w) * f3;
    }
    for (; j < n; j++) {
      int e0 = __shfl(idx, j, 32);
      float f0 = degF[e0];
      ushort4 u0 = *(const ushort4*)(base + (size_t)e0 * stride);
      s0.x += bf2f(u0.x) * f0; s0.y += bf2f(u0.y) * f0; s0.z += bf2f(u0.z) * f0; s0.w += bf2f(u0.w) * f0;
    }
  }
  return make_float4(s0.x + s1.x + s2.x + s3.x, s0.y + s1.y + s2.y + s3.y,
                     s0.z + s1.z + s2.z + s3.z, s0.w + s1.w + s2.w + s3.w);
}

template <int HEAD>
__global__ __launch_bounds__(256) void gather_kernel(Args a) {
  const int lane32 = threadIdx.x & 31;
  const int f = lane32 * 4;
  int blk = blockIdx.x;
  float v[4];
  float* outp;
  unsigned short* accp;

  if (blk < BGR_W) {
    int g = blk * 8 + (threadIdx.x >> 5);
    int c1 = a.cur[g];
    int c2 = a.cur[50000 + g];
    int c3 = a.cur[120000 + g];
    int l1 = c1 < C_WW ? c1 : C_WW;
    int l2 = c2 < C_WW ? c2 : C_WW;
    int l3 = c3 < C_DWR ? c3 : C_DWR;
    float4 s1 = edge_sum32(a.h_w3 + f, 384, a.csr_ww, a.degF, g * C_WW, g * C_WW + l1, lane32);
    float4 s2 = edge_sum32(a.h_w3 + 128 + f, 384, a.csr_wwr, a.degF + 50000, g * C_WW, g * C_WW + l2, lane32);
    float4 s3 = edge_sum32(a.h_d + f, 128, a.csr_dwr, a.degF + 150000, g * C_DWR, g * C_DWR + l3, lane32);
    float r1 = rsqrtf(fmaxf((float)c1, 1.f));
    float r2 = rsqrtf(fmaxf((float)c2, 1.f));
    float r3 = rsqrtf(fmaxf((float)c3, 1.f));
    const float* b0 = HEAD ? a.b2_ww : a.b1_ww;
    const float* b1 = HEAD ? a.b2_wwr : a.b1_wwr;
    const float* b2 = HEAD ? a.b2_dwr : a.b1_dwr;
#pragma unroll
    for (int i = 0; i < 4; i++) {
      float bb = b0[f + i] + b1[f + i] + b2[f + i];
      v[i] = fmaxf((&s1.x)[i] * r1 + (&s2.x)[i] * r2 + (&s3.x)[i] * r3 + bb, 0.f);
    }
    outp = a.out + g;
    accp = a.accW1 + (size_t)g * 128 + f;
  } else {
    int g = (blk - BGR_W) * 8 + (threadIdx.x >> 5);
    int c1 = a.cur[100000 + g];
    int l1 = c1 < C_WD ? c1 : C_WD;
    float4 s1 = edge_sum32(a.h_w3 + 256 + f, 384, a.csr_wd, a.degF + 100000, g * C_WD, g * C_WD + l1, lane32);
    float r1 = rsqrtf(fmaxf((float)c1, 1.f));
    const float* b0 = HEAD ? a.b2_wd : a.b1_wd;
#pragma unroll
    for (int i = 0; i < 4; i++)
      v[i] = fmaxf((&s1.x)[i] * r1 + b0[f + i], 0.f);
    outp = a.out + N_W + g;
    accp = a.accD1 + (size_t)g * 128 + f;
  }

  if (HEAD) {
    float4 w4 = *(const float4*)(a.lin_w + f);
    float p = v[0] * w4.x + v[1] * w4.y + v[2] * w4.z + v[3] * w4.w;
#pragma unroll
    for (int off = 16; off > 0; off >>= 1) p += __shfl_down(p, off, 32);
    if (lane32 == 0) *outp = 1.0f / (1.0f + expf(-(p + a.lin_b[0])));
  } else {
    ushort4 o;
    o.x = f2bf(v[0]); o.y = f2bf(v[1]); o.z = f2bf(v[2]); o.w = f2bf(v[3]);
    *(ushort4*)accp = o;
  }
}

// ----------------------------------------------------------------- launch ---
extern "C" void kernel_launch(void* const* d_in, const int* in_sizes, int n_in,
                              void* d_out, int out_size, void* d_ws, size_t ws_size,
                              hipStream_t stream) {
  Args a;
  a.x_word = (const float*)d_in[0];
  a.x_doc  = (const float*)d_in[1];
  a.src_ww  = (const int*)d_in[2];
  a.dst_ww  = (const int*)d_in[3];
  a.src_wd  = (const int*)d_in[4];
  a.dst_wd  = (const int*)d_in[5];
  a.src_wwr = (const int*)d_in[6];
  a.dst_wwr = (const int*)d_in[7];
  a.src_dwr = (const int*)d_in[8];
  a.dst_dwr = (const int*)d_in[9];
  a.W1_ww  = (const float*)d_in[10]; a.b1_ww  = (const float*)d_in[11];
  a.W1_wd  = (const float*)d_in[12]; a.b1_wd  = (const float*)d_in[13];
  a.W1_wwr = (const float*)d_in[14]; a.b1_wwr = (const float*)d_in[15];
  a.W1_dwr = (const float*)d_in[16]; a.b1_dwr = (const float*)d_in[17];
  a.W2_ww  = (const float*)d_in[18]; a.b2_ww  = (const float*)d_in[19];
  a.W2_wd  = (const float*)d_in[20]; a.b2_wd  = (const float*)d_in[21];
  a.W2_wwr = (const float*)d_in[22]; a.b2_wwr = (const float*)d_in[23];
  a.W2_dwr = (const float*)d_in[24]; a.b2_dwr = (const float*)d_in[25];
  a.lin_w  = (const float*)d_in[26];
  a.lin_b  = (const float*)d_in[27];
  a.out = (float*)d_out;

  // ---- workspace layout (4-byte units) ----
  char* ws = (char*)d_ws;
  size_t off = 0;
  auto alloc = [&](size_t n4) { void* p = ws + off * 4; off += n4; return p; };
  a.cnt256d = (int*)alloc(1024);   // zeroed
  a.cnt256s = (int*)alloc(1024);   // zeroed
  const size_t zero4 = off;        // 8 KB
  a.cur  = (int*)alloc(NTOT);
  a.degF = (float*)alloc(NTOT);
  a.csr_ww  = (unsigned short*)alloc((size_t)NB_WW * 256 * C_WW / 2);
  a.csr_wwr = (unsigned short*)alloc((size_t)NB_WW * 256 * C_WW / 2);
  a.csr_wd  = (unsigned short*)alloc((size_t)NB_WD * 256 * C_WD / 2);
  a.csr_dwr = (unsigned short*)alloc((size_t)NB_DWR * 256 * C_DWR / 2);
  a.xw_bf = (unsigned short*)alloc((size_t)N_W * 256 / 2);
  a.xd_bf = (unsigned short*)alloc((size_t)N_D * 256 / 2);
  a.h_w3  = (unsigned short*)alloc((size_t)N_W * 384 / 2);
  a.h_d   = (unsigned short*)alloc((size_t)N_D * 128 / 2);
  a.Bt1w  = (unsigned short*)alloc(384 * 256 / 2);
  a.Bt1d  = (unsigned short*)alloc(128 * 256 / 2);
  a.Bt2w  = (unsigned short*)alloc(384 * 128 / 2);
  a.Bt2d  = (unsigned short*)alloc(128 * 128 / 2);
  a.accW1 = a.xw_bf;
  a.accD1 = a.xw_bf + (size_t)N_W * 128;
  // staging aliases head of h_w3 (dead until mid's gemm writes it AFTER
  // pass2 consumed it? NO — pass2 and gemm1 now share a dispatch, and gemm1
  // writes h_w3 while pass2 reads staging. Move staging to its own region.
  unsigned int* stg = (unsigned int*)alloc((size_t)(2 * NB_WW * CAPB_WW + NB_WD * CAPB_WD + NB_DWR * CAPB_DWR));
  a.stg_ww  = stg;  stg += (size_t)NB_WW * CAPB_WW;
  a.stg_wwr = stg;  stg += (size_t)NB_WW * CAPB_WW;
  a.stg_wd  = stg;  stg += (size_t)NB_WD * CAPB_WD;
  a.stg_dwr = stg;
  unsigned char* sstg = (unsigned char*)alloc((NBS_W * (2 * CAPS_WW + CAPS_WD) + NBS_D * CAPS_DWR + 3) / 4);
  a.sst_ww  = sstg; sstg += (size_t)NBS_W * CAPS_WW;
  a.sst_wwr = sstg; sstg += (size_t)NBS_W * CAPS_WW;
  a.sst_wd  = sstg; sstg += (size_t)NBS_W * CAPS_WD;
  a.sst_dwr = sstg;
  (void)ws_size;

  hipMemsetAsync(d_ws, 0, zero4 * 4, stream);

  prep1_kernel<<<2 * BS_WW + 2 * BS_WD + BV_W + BV_D + BP1W + BP1D + BP2W + BP2D,
                 256, 0, stream>>>(a);
  mid_kernel<<<2 * NB_WW + NB_WD + NB_DWR + 3 * NBS_W + NBS_D + 3 * BG_W + BG_D,
               256, 0, stream>>>(a);
  gather_kernel<0><<<BGR_W + BGR_D, 256, 0, stream>>>(a);
  gemm2_kernel<<<3 * BG_W + BG_D, 256, 0, stream>>>(a);
  gather_kernel<1><<<BGR_W + BGR_D, 256, 0, stream>>>(a);
}